// Round 8
// baseline (72.247 us; speedup 1.0000x reference)
//
#include <hip/hip_runtime.h>

#define IN_DIM   256
#define OUT_DIM  128
#define IN_SEQ   512
#define OUT_SEQ  512
#define NUM_BASIS 16
#define LN_EPS   1e-5f

__device__ __forceinline__ float cosrev(float x) {
  // cos(2*pi*x): v_fract then v_cos (revolutions semantics)
  return __builtin_amdgcn_cosf(__builtin_amdgcn_fractf(x));
}

// ---------------------------------------------------------------------------
// Kernel 1: Z = x @ M.T (one block per k), LayerNorm.
// Writes ZnT[j][k] (normalized, TRANSPOSED -> k_pos reads coalesced by k)
// and V[k][i] = pre-LN z (the residual base that k_pos atomically adds onto).
// ---------------------------------------------------------------------------
__global__ __launch_bounds__(256) void k_prep(const float* __restrict__ x,
                                              const float* __restrict__ M,
                                              const float* __restrict__ gamma,
                                              const float* __restrict__ beta,
                                              float* __restrict__ ZnT,
                                              float* __restrict__ V) {
  const int k = blockIdx.x;
  const int t = threadIdx.x;
  __shared__ __align__(16) float xk[IN_DIM];
  __shared__ float red[256];
  __shared__ float stats[8];

  xk[t] = x[k * IN_DIM + t];
  __syncthreads();

  const int j = t & 127;
  const int h = t >> 7;  // which half of the 256-dim input
  const float4* __restrict__ M4 =
      reinterpret_cast<const float4*>(M + j * IN_DIM + h * 128);
  const float4* __restrict__ x4 = reinterpret_cast<const float4*>(xk + h * 128);
  float acc = 0.f;
#pragma unroll 8
  for (int c = 0; c < 32; ++c) {
    float4 m = M4[c];
    float4 xv = x4[c];
    acc = fmaf(m.x, xv.x, acc);
    acc = fmaf(m.y, xv.y, acc);
    acc = fmaf(m.z, xv.z, acc);
    acc = fmaf(m.w, xv.w, acc);
  }
  red[t] = acc;
  __syncthreads();

  float z = 0.f;
  if (t < 128) z = red[t] + red[t + 128];

  float s1 = (t < 128) ? z : 0.f;
  float s2 = (t < 128) ? z * z : 0.f;
#pragma unroll
  for (int m = 1; m < 64; m <<= 1) {
    s1 += __shfl_xor(s1, m);
    s2 += __shfl_xor(s2, m);
  }
  const int w = t >> 6;
  if ((t & 63) == 0) {
    stats[w] = s1;
    stats[4 + w] = s2;
  }
  __syncthreads();
  const float mu  = (stats[0] + stats[1] + stats[2] + stats[3]) * (1.f / 128.f);
  const float msq = (stats[4] + stats[5] + stats[6] + stats[7]) * (1.f / 128.f);
  const float rs  = rsqrtf(msq - mu * mu + LN_EPS);

  if (t < 128) {
    float zn = (z - mu) * rs * gamma[t] + beta[t];
    ZnT[t * IN_SEQ + k] = zn;      // transposed (scattered 4B, tiny total)
    V[k * OUT_DIM + t]  = z;       // coalesced; residual base for k_pos
  }
}

// ---------------------------------------------------------------------------
// Kernel 2: position transform, direct cos, k-in-lane.
// Block = (g-pair gp 0..7, channel i 0..127); 256 threads; thread owns
// k in {t, t+256}. For each (j, g): p = i*2048 + j*16 + g + 2 and P[i,j,g]
// are WAVE-UNIFORM -> scalar loads / scalar rcp feed; Zn comes from ZnT
// coalesced by k. Accumulation is thread-private (no shfl, no LDS, ~32 VGPR
// of state — nothing for the allocator to demote; rounds 5-7's Chebyshev
// state was frontend-demoted to scratch: WRITE_SIZE 8MB = 64B/thread).
// Each block atomically adds its (i, 2-g) partial column onto V.
// ---------------------------------------------------------------------------
__global__ __launch_bounds__(256) void k_pos(const float* __restrict__ P,
                                             const float* __restrict__ ZnT,
                                             float* __restrict__ V) {
  const int gp = blockIdx.x;      // g-pair 0..7
  const int i  = blockIdx.y;      // 0..127
  const int t  = threadIdx.x;     // k-lane
  const float kf0 = (float)t;
  const float kf1 = (float)(t + 256);
  const int g0 = gp * 2;
  const int pbase = i * (OUT_DIM * NUM_BASIS) + g0 + 2;   // + j*16 (+1)
  const float* __restrict__ Prow = P + (size_t)i * OUT_DIM * NUM_BASIS + g0;

  float acc0 = 0.f, acc1 = 0.f;
#pragma unroll 2
  for (int j = 0; j < OUT_DIM; ++j) {
    const float z0 = ZnT[j * IN_SEQ + t];          // coalesced, L2-resident
    const float z1 = ZnT[j * IN_SEQ + t + 256];
    {  // g = g0
      const float pinv = __builtin_amdgcn_rcpf((float)(pbase + j * 16));
      const float Pw = Prow[j * NUM_BASIS];        // uniform -> s_load
      acc0 = fmaf(Pw * z0, cosrev(kf0 * pinv), acc0);
      acc1 = fmaf(Pw * z1, cosrev(kf1 * pinv), acc1);
    }
    {  // g = g0 + 1
      const float pinv = __builtin_amdgcn_rcpf((float)(pbase + j * 16 + 1));
      const float Pw = Prow[j * NUM_BASIS + 1];    // uniform -> s_load
      acc0 = fmaf(Pw * z0, cosrev(kf0 * pinv), acc0);
      acc1 = fmaf(Pw * z1, cosrev(kf1 * pinv), acc1);
    }
  }
  atomicAdd(&V[(size_t)t * OUT_DIM + i], acc0);
  atomicAdd(&V[(size_t)(t + 256) * OUT_DIM + i], acc1);
}

// ---------------------------------------------------------------------------
// Kernel 3: out[s,:] = sum_k L[k,s] * V[k,:].  Block = s; 256 threads =
// (i, k-half). L[k,s] is wave-uniform -> s_load; V rows coalesced (L2).
// Direct store, no atomics, no zero-init of out anywhere.
// ---------------------------------------------------------------------------
__global__ __launch_bounds__(256) void k_seq(const float* __restrict__ L,
                                             const float* __restrict__ V,
                                             float* __restrict__ out) {
  const int s = blockIdx.x;
  const int t = threadIdx.x;
  const int i = t & 127;
  const int q = t >> 7;
  __shared__ float red[2 * OUT_DIM];

  const int k0 = q * 256;
  float acc = 0.f;
#pragma unroll 8
  for (int kk = 0; kk < 256; ++kk) {
    const int k = k0 + kk;
    acc = fmaf(L[(size_t)k * OUT_SEQ + s],          // uniform -> s_load
               V[(size_t)k * OUT_DIM + i], acc);    // coalesced
  }
  red[q * OUT_DIM + i] = acc;
  __syncthreads();

  if (t < OUT_DIM)
    out[(size_t)s * OUT_DIM + t] = red[t] + red[OUT_DIM + t];
}

extern "C" void kernel_launch(void* const* d_in, const int* in_sizes, int n_in,
                              void* d_out, int out_size, void* d_ws, size_t ws_size,
                              hipStream_t stream) {
  const float* x      = (const float*)d_in[0];
  const float* M      = (const float*)d_in[1];
  const float* P      = (const float*)d_in[2];
  const float* Linker = (const float*)d_in[3];
  const float* gamma  = (const float*)d_in[4];
  const float* beta   = (const float*)d_in[5];
  // d_in[6] = periods (recomputed inline: p = i*2048 + j*16 + g + 2, exact in f32)
  float* out = (float*)d_out;

  float* ws  = (float*)d_ws;
  float* ZnT = ws;                        // [128 j][512 k] normalized, transposed
  float* V   = ws + OUT_DIM * IN_SEQ;     // [512 k][128 i], init = pre-LN Z

  k_prep<<<dim3(IN_SEQ), dim3(256), 0, stream>>>(x, M, gamma, beta, ZnT, V);
  k_pos<<<dim3(NUM_BASIS / 2, OUT_DIM), dim3(256), 0, stream>>>(P, ZnT, V);
  k_seq<<<dim3(OUT_SEQ), dim3(256), 0, stream>>>(Linker, V, out);
}

// Round 9
// 55.622 us; speedup vs baseline: 1.2989x; 1.2989x over previous
//
#include <hip/hip_runtime.h>

#define IN_DIM   256
#define OUT_DIM  128
#define IN_SEQ   512
#define OUT_SEQ  512
#define NUM_BASIS 16
#define LN_EPS   1e-5f

__device__ __forceinline__ float cosrev(float x) {
  // cos(2*pi*x): v_fract then v_cos (revolutions semantics)
  return __builtin_amdgcn_cosf(__builtin_amdgcn_fractf(x));
}

// ---------------------------------------------------------------------------
// Kernel 1: Z = x @ M.T (one block per k), LayerNorm.
// Writes ZnT[j][k] (normalized, transposed -> k_pos reads coalesced by k),
// V[k][i] = pre-LN z (residual base k_pos adds onto), and the pairs table
// pairs[e] = {P[e], 1/(e+2)} — note p(i,j,g) = i*2048 + j*16 + g + 2 is
// exactly flat_index + 2, so table init is two coalesced lines. Hoisting the
// rcp out of k_pos's inner loop removes 2 quarter-rate v_rcp per j (round-8's
// biggest modeled stall contributor after load latency).
// ---------------------------------------------------------------------------
__global__ __launch_bounds__(256) void k_prep(const float* __restrict__ x,
                                              const float* __restrict__ M,
                                              const float* __restrict__ P,
                                              const float* __restrict__ gamma,
                                              const float* __restrict__ beta,
                                              float* __restrict__ ZnT,
                                              float* __restrict__ V,
                                              float2* __restrict__ pairs) {
  const int k = blockIdx.x;
  const int t = threadIdx.x;
  __shared__ __align__(16) float xk[IN_DIM];
  __shared__ float red[256];
  __shared__ float stats[8];

  // pairs table: 2 entries per thread, fully coalesced
  {
    const int e0 = k * 512 + t;
    const int e1 = e0 + 256;
    pairs[e0] = make_float2(P[e0], __builtin_amdgcn_rcpf((float)(e0 + 2)));
    pairs[e1] = make_float2(P[e1], __builtin_amdgcn_rcpf((float)(e1 + 2)));
  }

  xk[t] = x[k * IN_DIM + t];
  __syncthreads();

  const int j = t & 127;
  const int h = t >> 7;  // which half of the 256-dim input
  const float4* __restrict__ M4 =
      reinterpret_cast<const float4*>(M + j * IN_DIM + h * 128);
  const float4* __restrict__ x4 = reinterpret_cast<const float4*>(xk + h * 128);
  float acc = 0.f;
#pragma unroll 8
  for (int c = 0; c < 32; ++c) {
    float4 m = M4[c];
    float4 xv = x4[c];
    acc = fmaf(m.x, xv.x, acc);
    acc = fmaf(m.y, xv.y, acc);
    acc = fmaf(m.z, xv.z, acc);
    acc = fmaf(m.w, xv.w, acc);
  }
  red[t] = acc;
  __syncthreads();

  float z = 0.f;
  if (t < 128) z = red[t] + red[t + 128];

  float s1 = (t < 128) ? z : 0.f;
  float s2 = (t < 128) ? z * z : 0.f;
#pragma unroll
  for (int m = 1; m < 64; m <<= 1) {
    s1 += __shfl_xor(s1, m);
    s2 += __shfl_xor(s2, m);
  }
  const int w = t >> 6;
  if ((t & 63) == 0) {
    stats[w] = s1;
    stats[4 + w] = s2;
  }
  __syncthreads();
  const float mu  = (stats[0] + stats[1] + stats[2] + stats[3]) * (1.f / 128.f);
  const float msq = (stats[4] + stats[5] + stats[6] + stats[7]) * (1.f / 128.f);
  const float rs  = rsqrtf(msq - mu * mu + LN_EPS);

  if (t < 128) {
    float zn = (z - mu) * rs * gamma[t] + beta[t];
    ZnT[t * IN_SEQ + k] = zn;      // transposed (scattered 4B, tiny total)
    V[k * OUT_DIM + t]  = z;       // coalesced; residual base for k_pos
  }
}

// ---------------------------------------------------------------------------
// Kernel 2: position transform, direct cos, k-in-lane, NO atomics.
// Block = (k-slice ks 0..7, channel i 0..127): the block owns its (k,i)
// outputs completely (all j, all g) -> single-writer += on V.
// Thread = (k-local 0..63, g-quad 0..3); gq forced wave-uniform via
// readfirstlane so the 4 pair loads per j become one s_load_dwordx8.
// Per j per lane: 1 coalesced z load + 4x(mul,fract,cos,fma) + 1 fma.
// Epilogue: 4 g-quad partials reduced through 1KB LDS, V[k][i] += T.
// ---------------------------------------------------------------------------
__global__ __launch_bounds__(256) void k_pos(const float2* __restrict__ pairs,
                                             const float* __restrict__ ZnT,
                                             float* __restrict__ V) {
  const int ks = blockIdx.x;   // 0..7
  const int i  = blockIdx.y;   // 0..127
  const int t  = threadIdx.x;
  const int kl = t & 63;
  const int gq = __builtin_amdgcn_readfirstlane(t >> 6);  // wave-uniform 0..3
  const int k  = ks * 64 + kl;
  const float kf = (float)k;

  const float2* __restrict__ pj = pairs + (size_t)i * (OUT_DIM * NUM_BASIS) + gq * 4;
  const float*  __restrict__ zj = ZnT + k;

  float acc = 0.f;
#pragma unroll 8
  for (int j = 0; j < OUT_DIM; ++j) {
    const float z = zj[j * IN_SEQ];             // coalesced 256B/wave, L2-res
    const float2 q0 = pj[j * NUM_BASIS + 0];    // uniform -> s_load_dwordx8
    const float2 q1 = pj[j * NUM_BASIS + 1];
    const float2 q2 = pj[j * NUM_BASIS + 2];
    const float2 q3 = pj[j * NUM_BASIS + 3];
    float s = q0.x * cosrev(kf * q0.y);
    s = fmaf(q1.x, cosrev(kf * q1.y), s);
    s = fmaf(q2.x, cosrev(kf * q2.y), s);
    s = fmaf(q3.x, cosrev(kf * q3.y), s);
    acc = fmaf(z, s, acc);
  }

  __shared__ float red[4][64];
  red[gq][kl] = acc;
  __syncthreads();
  if (t < 64) {
    const int kk = ks * 64 + t;
    V[(size_t)kk * OUT_DIM + i] += red[0][t] + red[1][t] + red[2][t] + red[3][t];
  }
}

// ---------------------------------------------------------------------------
// Kernel 3: out[s,:] = sum_k L[k,s] * V[k,:]. 2 s-rows per block (halves the
// V L2 re-read vs 1 row/block). L loads are block-uniform -> s_load_dwordx2;
// V rows coalesced. Direct store, no atomics, no zero-init.
// ---------------------------------------------------------------------------
__global__ __launch_bounds__(256) void k_seq(const float* __restrict__ L,
                                             const float* __restrict__ V,
                                             float* __restrict__ out) {
  const int s0 = blockIdx.x * 2;
  const int t  = threadIdx.x;
  const int i  = t & 127;
  const int q  = t >> 7;            // k-half
  __shared__ float red[2][2][OUT_DIM];   // [q][s-local][i]

  const int kb = q * 256;
  float a0 = 0.f, a1 = 0.f;
#pragma unroll 8
  for (int kk = 0; kk < 256; ++kk) {
    const int k = kb + kk;
    const float v = V[(size_t)k * OUT_DIM + i];          // coalesced
    a0 = fmaf(L[(size_t)k * OUT_SEQ + s0], v, a0);       // uniform s_loads
    a1 = fmaf(L[(size_t)k * OUT_SEQ + s0 + 1], v, a1);
  }
  red[q][0][i] = a0;
  red[q][1][i] = a1;
  __syncthreads();

  // thread (q,i) writes out[s0+q][i]
  out[(size_t)(s0 + q) * OUT_DIM + i] = red[0][q][i] + red[1][q][i];
}

extern "C" void kernel_launch(void* const* d_in, const int* in_sizes, int n_in,
                              void* d_out, int out_size, void* d_ws, size_t ws_size,
                              hipStream_t stream) {
  const float* x      = (const float*)d_in[0];
  const float* M      = (const float*)d_in[1];
  const float* P      = (const float*)d_in[2];
  const float* Linker = (const float*)d_in[3];
  const float* gamma  = (const float*)d_in[4];
  const float* beta   = (const float*)d_in[5];
  // d_in[6] = periods (recomputed inline: p = flat(i,j,g) + 2, exact in f32)
  float* out = (float*)d_out;

  float* ws  = (float*)d_ws;
  float* ZnT   = ws;                          // [128 j][512 k]
  float* V     = ws + OUT_DIM * IN_SEQ;       // [512 k][128 i], init = pre-LN Z
  float2* pairs = (float2*)(ws + 2 * OUT_DIM * IN_SEQ);  // [i][j][g] {P, 1/p}

  k_prep<<<dim3(IN_SEQ), dim3(256), 0, stream>>>(x, M, P, gamma, beta, ZnT, V, pairs);
  k_pos<<<dim3(8, OUT_DIM), dim3(256), 0, stream>>>(pairs, ZnT, V);
  k_seq<<<dim3(OUT_SEQ / 2), dim3(256), 0, stream>>>(Linker, V, out);
}